// Round 12
// baseline (219.786 us; speedup 1.0000x reference)
//
#include <hip/hip_runtime.h>
#include <math.h>

#define GAMMA 0.5f

constexpr int B_ = 16;
constexpr int N_ = 2048;
constexpr int M_ = 2048;
constexpr int S_ = 2049;                      // N+1 == M+1
constexpr long long PLANE = (long long)S_ * S_;

constexpr int Q_      = 8;     // contiguous columns per lane
constexpr int RPB     = 16;    // rows per block (all 4 waves share each row)
constexpr int NSTRIPE = 129;   // 128*16 = 2048 rows + stripe 128 = row 2048

// D (doubles): [0]G1 [1]G2 [2]G1r [3]G2r [4]G1c [5]G2c [6]X0 [7]X1
//   [8..23] aL per batch  [24]P0 [25]P0q [26]P1 [27]P1q  [28](int) counter
constexpr int NDBL = 32;

typedef float f4u __attribute__((ext_vector_type(4), aligned(4)));   // 4B-aligned
typedef float f4a __attribute__((ext_vector_type(4)));               // 16B-aligned

// ---------------------------------------------------------------------------
// Kernel 1: gather pos0/pos1, zero colC, accumulate P0/P1 moments.
// Grid exactly 256 blocks x 256 thr (blocks 0-127: pos0, 128-255: pos1).
// D must be pre-zeroed (hipMemsetAsync) since we atomicAdd here.
// ---------------------------------------------------------------------------
__global__ void gather_pos(const float* __restrict__ scores,
                           const int* __restrict__ gt0,
                           const int* __restrict__ gt1,
                           float* __restrict__ pos0,
                           float* __restrict__ pos1,
                           float* __restrict__ colC,
                           double* __restrict__ D) {
  const int idx  = blockIdx.x * blockDim.x + threadIdx.x;
  const int tid  = threadIdx.x;
  const int lane = tid & 63;
  const int w    = tid >> 6;
  const int total = B_ * N_;

  float v;
  if (idx < total) {
    colC[idx] = 0.0f;
    int b = idx >> 11;
    int i = idx & (N_ - 1);
    int g = gt0[idx];
    if (g == -1) g = M_;
    v = scores[(long long)b * PLANE + (long long)i * S_ + g];
    pos0[idx] = v;
  } else {
    int k = idx - total;
    int b = k >> 11;
    int j = k & (M_ - 1);
    int g = gt1[k];
    if (g == -1) g = N_;
    v = scores[(long long)b * PLANE + (long long)g * S_ + j];
    pos1[k] = v;
  }

  // block-uniform phase: blocks 0-127 are pos0, 128-255 pos1
  float m = v, q = v * v;
#pragma unroll
  for (int off = 32; off; off >>= 1) {
    m += __shfl_xor(m, off, 64);
    q += __shfl_xor(q, off, 64);
  }
  __shared__ float redP[4][2];
  if (lane == 0) { redP[w][0] = m; redP[w][1] = q; }
  __syncthreads();
  if (tid < 2) {
    const int phase = (blockIdx.x >= 128) ? 1 : 0;
    double s = (double)redP[0][tid] + (double)redP[1][tid] +
               (double)redP[2][tid] + (double)redP[3][tid];
    atomicAdd(&D[24 + 2 * phase + tid], s);
  }
}

// ---------------------------------------------------------------------------
// Kernel 2: main sweep. Wave w covers cols [512w, 512w+512); the 4 waves of a
// block read the SAME row -> fully contiguous 8KB per row step. Block owns 16
// complete rows -> row logs computed in-kernel (rowPart eliminated). Column
// clamp sums are block-disjoint -> direct atomics. Inner body = R10 verbatim.
// Grid (129 stripes, 16 b), 256 threads.
// ---------------------------------------------------------------------------
__launch_bounds__(256, 8)
__global__ void margin_main(const float* __restrict__ scores,
                            const float* __restrict__ pos0,
                            const float* __restrict__ pos1,
                            float* __restrict__ colC,      // [B][M] (atomic)
                            double* __restrict__ D) {
  const int st   = blockIdx.x;
  const int b    = blockIdx.y;
  const int i0   = st * RPB;
  const int tid  = threadIdx.x;
  const int lane = tid & 63;
  const int w    = tid >> 6;
  const int jbase = w * 512 + 8 * lane;     // 0..2040

  __shared__ float lp0[RPB];
  __shared__ float ldsR[RPB][4];            // per-row, per-wave clamp partials
  __shared__ float ldsM[4][8];

  if (tid < RPB) {
    int i = i0 + tid;
    lp0[tid] = (i < N_) ? pos0[b * N_ + i] : 0.0f;   // p0 = 0 for row 2048
  }

  float p1[Q_], cC[Q_];
  {
    const f4a plo = *(const f4a*)&pos1[b * M_ + jbase];
    const f4a phi = *(const f4a*)&pos1[b * M_ + jbase + 4];
    p1[0] = plo[0]; p1[1] = plo[1]; p1[2] = plo[2]; p1[3] = plo[3];
    p1[4] = phi[0]; p1[5] = phi[1]; p1[6] = phi[2]; p1[7] = phi[3];
  }
#pragma unroll
  for (int q = 0; q < Q_; ++q) cC[q] = 0.0f;
  float gs = 0.f, gq = 0.f, gsr = 0.f, gqr = 0.f,
        gsc = 0.f, gqc = 0.f, x0 = 0.f, x1 = 0.f;

  __syncthreads();

  int rmax = S_ - i0;
  rmax = rmax < 0 ? 0 : (rmax > RPB ? RPB : rmax);
  const float* rowp = scores + (long long)b * PLANE + (long long)i0 * S_ + jbase;
  const bool exlane = (w == 3) && (lane == 63);      // jbase=2040 -> rowp[8]=col 2048

#pragma unroll 2
  for (int r = 0; r < rmax; ++r) {
    const int i = i0 + r;
    const float p0 = lp0[r];
    const bool lastrow = (i == N_);

    const f4u v0 = *(const f4u*)(rowp);        // cols jbase..jbase+3
    const f4u v1 = *(const f4u*)(rowp + 4);    // cols jbase+4..jbase+7
    float s[Q_];
    s[0] = v0[0]; s[1] = v0[1]; s[2] = v0[2]; s[3] = v0[3];
    s[4] = v1[0]; s[5] = v1[1]; s[6] = v1[2]; s[7] = v1[3];
    float extra = 0.0f;
    if (exlane) extra = rowp[8];               // column 2048

    float rC = 0.0f;
#pragma unroll
    for (int q = 0; q < Q_; ++q) {
      const float sv = s[q];
      const float sg = sv + GAMMA;
      rC += fmaxf(sg - p0, 0.0f);          // row clamp
      x0  = fmaf(p0, sv, x0);              // row cross (0 on lastrow)
      cC[q] += fmaxf(sg - p1[q], 0.0f);    // col clamp (row 2048 included)
      x1  = fmaf(p1[q], sv, x1);           // col cross
      gs += sv;
      gq  = fmaf(sv, sv, gq);
      if (lastrow) { gsr += sv; gqr = fmaf(sv, sv, gqr); }
    }
    if (exlane) {                          // col 2048: row pass + G1c/G2c
      rC  += fmaxf(extra + GAMMA - p0, 0.0f);
      x0   = fmaf(p0, extra, x0);
      gs  += extra; gq  = fmaf(extra, extra, gq);
      gsc += extra; gqc = fmaf(extra, extra, gqc);
      if (lastrow) { gsr += extra; gqr = fmaf(extra, extra, gqr); }
    }

#pragma unroll
    for (int off = 32; off; off >>= 1) rC += __shfl_xor(rC, off, 64);
    if (lane == 0 && !lastrow) ldsR[r][w] = rC;
    rowp += S_;
  }

  // ---- moments wave-reduce ----
  float m0 = gs, m1 = gq, m2 = gsr, m3 = gqr, m4 = gsc, m5 = gqc, m6 = x0, m7 = x1;
#pragma unroll
  for (int off = 32; off; off >>= 1) {
    m0 += __shfl_xor(m0, off, 64); m1 += __shfl_xor(m1, off, 64);
    m2 += __shfl_xor(m2, off, 64); m3 += __shfl_xor(m3, off, 64);
    m4 += __shfl_xor(m4, off, 64); m5 += __shfl_xor(m5, off, 64);
    m6 += __shfl_xor(m6, off, 64); m7 += __shfl_xor(m7, off, 64);
  }
  if (lane == 0) {
    ldsM[w][0] = m0; ldsM[w][1] = m1; ldsM[w][2] = m2; ldsM[w][3] = m3;
    ldsM[w][4] = m4; ldsM[w][5] = m5; ldsM[w][6] = m6; ldsM[w][7] = m7;
  }
  __syncthreads();

  // ---- row logs in-kernel (rows complete within block) ----
  {
    double aL = 0.0;
    if (tid < RPB) {
      int i = i0 + tid;
      if (i < N_) {
        float v = ldsR[tid][0] + ldsR[tid][1] + ldsR[tid][2] + ldsR[tid][3];
        aL = log((double)v + 0.5);         // log(rowGap + 1), gt term folded
      }
    }
    if (w == 0) {                           // reduce 16 doubles within wave 0
#pragma unroll
      for (int off = 8; off; off >>= 1) aL += __shfl_xor(aL, off, 64);
      if (lane == 0) atomicAdd(&D[8 + b], aL);
    }
  }

  // ---- column partials: block-disjoint cols -> direct atomics ----
#pragma unroll
  for (int q = 0; q < Q_; ++q)
    atomicAdd(&colC[b * M_ + jbase + q], cC[q]);

  if (tid < 8) {
    double v = (double)ldsM[0][tid] + (double)ldsM[1][tid] +
               (double)ldsM[2][tid] + (double)ldsM[3][tid];
    atomicAdd(&D[tid], v);
  }
}

// ---------------------------------------------------------------------------
// Kernel 3: column logs; last block computes variance + the 16 outputs.
// Grid (8 slices, 16 b) = 128 blocks, 256 threads.
// ---------------------------------------------------------------------------
__global__ void finalize_cols(const float* __restrict__ colC,
                              double* __restrict__ D,
                              float* __restrict__ out) {
  const int slice = blockIdx.x;
  const int b     = blockIdx.y;
  const int tid   = threadIdx.x;
  const int lane  = tid & 63;
  const int w     = tid >> 6;
  const int idx   = slice * 256 + tid;   // < 2048

  double aL = log((double)colC[b * M_ + idx] + 0.5);
#pragma unroll
  for (int off = 32; off; off >>= 1) aL += __shfl_xor(aL, off, 64);
  __shared__ double red[4];
  if (lane == 0) red[w] = aL;
  __syncthreads();
  if (tid == 0)
    atomicAdd(&D[8 + b], red[0] + red[1] + red[2] + red[3]);

  // ---- last-block completion: compute the 16 outputs ----
  __shared__ int lastFlag;
  if (tid == 0) {
    __threadfence();
    int* cnt = (int*)(D + 28);
    int old = __hip_atomic_fetch_add(cnt, 1, __ATOMIC_ACQ_REL,
                                     __HIP_MEMORY_SCOPE_AGENT);
    lastFlag = (old == 8 * B_ - 1);       // 128 blocks
  }
  __syncthreads();
  if (lastFlag && tid == 0) {
    double Dv[28];
    for (int k = 0; k < 28; ++k)
      Dv[k] = __hip_atomic_load(&D[k], __ATOMIC_RELAXED,
                                __HIP_MEMORY_SCOPE_AGENT);
    const double G1 = Dv[0], G2 = Dv[1], G1r = Dv[2], G2r = Dv[3];
    const double G1c = Dv[4], G2c = Dv[5], X0 = Dv[6], X1 = Dv[7];
    const double P0 = Dv[24], P0q = Dv[25], P1 = Dv[26], P1q = Dv[27];
    const double SM = 2.0 * G1 - G1r - G1c - 2049.0 * (P0 + P1);
    const double SQ = 2.0 * G2 - G2r - G2c - 2.0 * (X0 + X1)
                      + 2049.0 * (P0q + P1q);
    const double cnt_ = 134217728.0;     // 2*B*N*M
    const double var = (SQ - SM * SM / cnt_) / (cnt_ - 1.0);
    const double vl = log(var + 1.0);
    for (int k = 0; k < B_; ++k)
      out[k] = (float)(Dv[8 + k] / 4096.0 + vl);
  }
}

// ---------------------------------------------------------------------------
extern "C" void kernel_launch(void* const* d_in, const int* in_sizes, int n_in,
                              void* d_out, int out_size, void* d_ws, size_t ws_size,
                              hipStream_t stream) {
  const float* scores = (const float*)d_in[0];
  const int*   gt0    = (const int*)d_in[1];
  const int*   gt1    = (const int*)d_in[2];
  float*       out    = (float*)d_out;

  double* D    = (double*)d_ws;                     // 32 doubles (256 B)
  float* pos0  = (float*)((char*)d_ws + 256);
  float* pos1  = pos0 + (size_t)B_ * N_;
  float* colC  = pos1 + (size_t)B_ * M_;            // B*M floats

  hipMemsetAsync(D, 0, 256, stream);                // D + counter

  gather_pos<<<256, 256, 0, stream>>>(scores, gt0, gt1, pos0, pos1, colC, D);

  dim3 grid(NSTRIPE, B_);           // (129, 16) = 2064 blocks
  margin_main<<<grid, 256, 0, stream>>>(scores, pos0, pos1, colC, D);

  dim3 fgrid(8, B_);                // 128 blocks
  finalize_cols<<<fgrid, 256, 0, stream>>>(colC, D, out);
}

// Round 13
// 82.531 us; speedup vs baseline: 2.6631x; 2.6631x over previous
//
#include <hip/hip_runtime.h>
#include <math.h>

#define GAMMA 0.5f

constexpr int B_ = 16;
constexpr int N_ = 2048;
constexpr int M_ = 2048;
constexpr int S_ = 2049;                      // N+1 == M+1
constexpr long long PLANE = (long long)S_ * S_;

constexpr int Q_      = 8;     // contiguous columns per lane
constexpr int TILE_W  = 512;   // 64 lanes * 8 cols
constexpr int NTILE   = 4;     // col 2048 handled via "extra" lane-0 load
constexpr int RPW     = 16;    // rows per wave
constexpr int RPB     = 64;    // rows per block (4 waves)
constexpr int NSTRIPE = 33;    // ceil(2049/64)

// D (doubles): [0]G1 [1]G2 [2]G1r [3]G2r [4]G1c [5]G2c [6]X0 [7]X1
//   [8..23] aL per batch  [24]P0 [25]P0q [26]P1 [27]P1q  [28](int) counter
constexpr int NDBL = 32;

typedef float f4u __attribute__((ext_vector_type(4), aligned(4)));   // 4B-aligned
typedef float f4a __attribute__((ext_vector_type(4)));               // 16B-aligned

// ---------------------------------------------------------------------------
// Kernel 1: gather pos0/pos1, zero D accumulators (incl. counter) and colC.
// ---------------------------------------------------------------------------
__global__ void gather_pos(const float* __restrict__ scores,
                           const int* __restrict__ gt0,
                           const int* __restrict__ gt1,
                           float* __restrict__ pos0,
                           float* __restrict__ pos1,
                           float* __restrict__ colC,
                           double* __restrict__ D) {
  int idx = blockIdx.x * blockDim.x + threadIdx.x;
  if (idx < NDBL) D[idx] = 0.0;
  const int total = B_ * N_;
  if (idx < total) colC[idx] = 0.0f;          // B*M == B*N
  if (idx < total) {
    int b = idx >> 11;
    int i = idx & (N_ - 1);
    int g = gt0[idx];
    if (g == -1) g = M_;
    pos0[idx] = scores[(long long)b * PLANE + (long long)i * S_ + g];
  } else if (idx < 2 * total) {
    int k = idx - total;
    int b = k >> 11;
    int j = k & (M_ - 1);
    int g = gt1[k];
    if (g == -1) g = N_;
    pos1[k] = scores[(long long)b * PLANE + (long long)g * S_ + j];
  }
}

// ---------------------------------------------------------------------------
// Kernel 2: main sweep — R11 verbatim (proven 77.4 µs): contiguous per-lane
// dwordx4 loads, 11-op body, unroll 4, tile/stripe grid, col-atomics.
// Grid (4 tiles, 33 stripes, 16 b), 256 threads.
// ---------------------------------------------------------------------------
__launch_bounds__(256)
__global__ void margin_main(const float* __restrict__ scores,
                            const float* __restrict__ pos0,
                            const float* __restrict__ pos1,
                            float* __restrict__ rowPart,   // [NTILE][B][N]
                            float* __restrict__ colC,      // [B][M] (atomic)
                            double* __restrict__ D) {
  const int tile = blockIdx.x;
  const int st   = blockIdx.y;
  const int b    = blockIdx.z;
  const int i0   = st * RPB;
  const int j0   = tile * TILE_W;
  const int tid  = threadIdx.x;
  const int lane = tid & 63;
  const int w    = tid >> 6;
  const int jbase = j0 + 8 * lane;

  __shared__ float lp0[RPB];
  __shared__ float ldsC[4][TILE_W];   // 8 KB
  __shared__ float ldsM[4][8];

  if (tid < RPB) {
    int i = i0 + tid;
    lp0[tid] = (i < N_) ? pos0[b * N_ + i] : 0.0f;   // p0 = 0 for row 2048
  }

  float p1[Q_], cC[Q_];
  {
    const f4a plo = *(const f4a*)&pos1[b * M_ + jbase];
    const f4a phi = *(const f4a*)&pos1[b * M_ + jbase + 4];
    p1[0] = plo[0]; p1[1] = plo[1]; p1[2] = plo[2]; p1[3] = plo[3];
    p1[4] = phi[0]; p1[5] = phi[1]; p1[6] = phi[2]; p1[7] = phi[3];
  }
#pragma unroll
  for (int q = 0; q < Q_; ++q) cC[q] = 0.0f;
  float gs = 0.f, gq = 0.f, gsr = 0.f, gqr = 0.f,
        gsc = 0.f, gqc = 0.f, x0 = 0.f, x1 = 0.f;

  __syncthreads();

  const int ib = i0 + w * RPW;
  int rmax = S_ - ib;
  rmax = rmax < 0 ? 0 : (rmax > RPW ? RPW : rmax);
  const float* rowp = scores + (long long)b * PLANE + (long long)ib * S_ + jbase;
  const bool last_tile = (tile == NTILE - 1);

#pragma unroll 4
  for (int r = 0; r < rmax; ++r) {
    const int i = ib + r;
    const float p0 = lp0[w * RPW + r];
    const bool lastrow = (i == N_);

    const f4u v0 = *(const f4u*)(rowp);        // cols jbase..jbase+3
    const f4u v1 = *(const f4u*)(rowp + 4);    // cols jbase+4..jbase+7
    float s[Q_];
    s[0] = v0[0]; s[1] = v0[1]; s[2] = v0[2]; s[3] = v0[3];
    s[4] = v1[0]; s[5] = v1[1]; s[6] = v1[2]; s[7] = v1[3];
    float extra = 0.0f;
    if (last_tile && lane == 0) extra = rowp[TILE_W];   // column 2048

    float rC = 0.0f;
#pragma unroll
    for (int q = 0; q < Q_; ++q) {
      const float sv = s[q];
      const float sg = sv + GAMMA;
      rC += fmaxf(sg - p0, 0.0f);          // row clamp
      x0  = fmaf(p0, sv, x0);              // row cross (0 on lastrow)
      cC[q] += fmaxf(sg - p1[q], 0.0f);    // col clamp (row 2048 included)
      x1  = fmaf(p1[q], sv, x1);           // col cross
      gs += sv;
      gq  = fmaf(sv, sv, gq);
      if (lastrow) { gsr += sv; gqr = fmaf(sv, sv, gqr); }
    }
    if (last_tile && lane == 0) {          // col 2048: row pass + G1c/G2c
      rC  += fmaxf(extra + GAMMA - p0, 0.0f);
      x0   = fmaf(p0, extra, x0);
      gs  += extra; gq  = fmaf(extra, extra, gq);
      gsc += extra; gqc = fmaf(extra, extra, gqc);
      if (lastrow) { gsr += extra; gqr = fmaf(extra, extra, gqr); }
    }

#pragma unroll
    for (int off = 32; off; off >>= 1) rC += __shfl_xor(rC, off, 64);
    if (lane == 0 && !lastrow)
      rowPart[((long long)tile * B_ + b) * N_ + i] = rC;
    rowp += S_;
  }

  // ---- block-end reductions ----
  float m0 = gs, m1 = gq, m2 = gsr, m3 = gqr, m4 = gsc, m5 = gqc, m6 = x0, m7 = x1;
#pragma unroll
  for (int off = 32; off; off >>= 1) {
    m0 += __shfl_xor(m0, off, 64); m1 += __shfl_xor(m1, off, 64);
    m2 += __shfl_xor(m2, off, 64); m3 += __shfl_xor(m3, off, 64);
    m4 += __shfl_xor(m4, off, 64); m5 += __shfl_xor(m5, off, 64);
    m6 += __shfl_xor(m6, off, 64); m7 += __shfl_xor(m7, off, 64);
  }
  if (lane == 0) {
    ldsM[w][0] = m0; ldsM[w][1] = m1; ldsM[w][2] = m2; ldsM[w][3] = m3;
    ldsM[w][4] = m4; ldsM[w][5] = m5; ldsM[w][6] = m6; ldsM[w][7] = m7;
  }
  // contiguous per-lane columns: ldsC[w][8*lane + q]
#pragma unroll
  for (int q = 0; q < Q_; ++q) ldsC[w][8 * lane + q] = cC[q];

  __syncthreads();

  // cross-wave column reduce -> one atomicAdd per column (33 adds/address)
  {
    const float c0v = ldsC[0][tid] + ldsC[1][tid] + ldsC[2][tid] + ldsC[3][tid];
    const float c1v = ldsC[0][tid + 256] + ldsC[1][tid + 256] +
                      ldsC[2][tid + 256] + ldsC[3][tid + 256];
    atomicAdd(&colC[b * M_ + j0 + tid], c0v);
    atomicAdd(&colC[b * M_ + j0 + tid + 256], c1v);
  }
  if (tid < 8) {
    double v = (double)ldsM[0][tid] + (double)ldsM[1][tid] +
               (double)ldsM[2][tid] + (double)ldsM[3][tid];
    atomicAdd(&D[tid], v);
  }
}

// ---------------------------------------------------------------------------
// Kernel 3: logs + pos moments; last block computes the 16 outputs.
// Grid (8 slices, 16 b, 2 phases) = 256 blocks, 256 threads.
// ---------------------------------------------------------------------------
__global__ void finalize(const float* __restrict__ rowPart,
                         const float* __restrict__ colC,
                         const float* __restrict__ pos0,
                         const float* __restrict__ pos1,
                         double* __restrict__ D,
                         float* __restrict__ out) {
  const int slice = blockIdx.x;
  const int b     = blockIdx.y;
  const int phase = blockIdx.z;    // 0 = rows, 1 = cols
  const int tid   = threadIdx.x;
  const int lane  = tid & 63;
  const int w     = tid >> 6;
  const int idx   = slice * 256 + tid;   // always < 2048

  double aL, aP, aPq;
  if (phase == 0) {
    float r = 0.f;
#pragma unroll
    for (int t = 0; t < NTILE; ++t)
      r += rowPart[((long long)t * B_ + b) * N_ + idx];
    float p = pos0[b * N_ + idx];
    aL = log((double)r + 0.5);           // log(rowGap + 1), gt term folded
    aP = (double)p; aPq = (double)p * p;
  } else {
    float c = colC[b * M_ + idx];
    float p = pos1[b * M_ + idx];
    aL = log((double)c + 0.5);
    aP = (double)p; aPq = (double)p * p;
  }

#pragma unroll
  for (int off = 32; off; off >>= 1) {
    aL  += __shfl_xor(aL, off, 64);
    aP  += __shfl_xor(aP, off, 64);
    aPq += __shfl_xor(aPq, off, 64);
  }
  __shared__ double red[4][3];
  if (lane == 0) { red[w][0] = aL; red[w][1] = aP; red[w][2] = aPq; }
  __syncthreads();
  if (tid == 0) {
    atomicAdd(&D[8 + b], red[0][0] + red[1][0] + red[2][0] + red[3][0]);
    atomicAdd(&D[24 + 2 * phase], red[0][1] + red[1][1] + red[2][1] + red[3][1]);
    atomicAdd(&D[25 + 2 * phase], red[0][2] + red[1][2] + red[2][2] + red[3][2]);
  }

  // ---- last-block completion: compute the 16 outputs ----
  __shared__ int lastFlag;
  if (tid == 0) {
    __threadfence();
    int* cnt = (int*)(D + 28);
    int old = __hip_atomic_fetch_add(cnt, 1, __ATOMIC_ACQ_REL,
                                     __HIP_MEMORY_SCOPE_AGENT);
    lastFlag = (old == 8 * B_ * 2 - 1);
  }
  __syncthreads();
  if (lastFlag && tid == 0) {
    double Dv[28];
    for (int k = 0; k < 28; ++k)
      Dv[k] = __hip_atomic_load(&D[k], __ATOMIC_RELAXED,
                                __HIP_MEMORY_SCOPE_AGENT);
    const double G1 = Dv[0], G2 = Dv[1], G1r = Dv[2], G2r = Dv[3];
    const double G1c = Dv[4], G2c = Dv[5], X0 = Dv[6], X1 = Dv[7];
    const double P0 = Dv[24], P0q = Dv[25], P1 = Dv[26], P1q = Dv[27];
    const double SM = 2.0 * G1 - G1r - G1c - 2049.0 * (P0 + P1);
    const double SQ = 2.0 * G2 - G2r - G2c - 2.0 * (X0 + X1)
                      + 2049.0 * (P0q + P1q);
    const double cnt_ = 134217728.0;     // 2*B*N*M
    const double var = (SQ - SM * SM / cnt_) / (cnt_ - 1.0);
    const double vl = log(var + 1.0);
    for (int k = 0; k < B_; ++k)
      out[k] = (float)(Dv[8 + k] / 4096.0 + vl);
  }
}

// ---------------------------------------------------------------------------
extern "C" void kernel_launch(void* const* d_in, const int* in_sizes, int n_in,
                              void* d_out, int out_size, void* d_ws, size_t ws_size,
                              hipStream_t stream) {
  const float* scores = (const float*)d_in[0];
  const int*   gt0    = (const int*)d_in[1];
  const int*   gt1    = (const int*)d_in[2];
  float*       out    = (float*)d_out;

  double* D      = (double*)d_ws;                     // 32 doubles
  float* pos0    = (float*)((char*)d_ws + 256);
  float* pos1    = pos0 + (size_t)B_ * N_;
  float* rowPart = pos1 + (size_t)B_ * M_;            // NTILE*B*N
  float* colC    = rowPart + (size_t)NTILE * B_ * N_; // B*M

  const int gth = 2 * B_ * N_;
  gather_pos<<<(gth + 255) / 256, 256, 0, stream>>>(scores, gt0, gt1,
                                                    pos0, pos1, colC, D);

  dim3 grid(NTILE, NSTRIPE, B_);    // (4, 33, 16)
  margin_main<<<grid, 256, 0, stream>>>(scores, pos0, pos1,
                                        rowPart, colC, D);

  dim3 fgrid(8, B_, 2);
  finalize<<<fgrid, 256, 0, stream>>>(rowPart, colC, pos0, pos1, D, out);
}

// Round 14
// 76.919 us; speedup vs baseline: 2.8574x; 1.0730x over previous
//
#include <hip/hip_runtime.h>
#include <math.h>

#define GAMMA 0.5f

constexpr int B_ = 16;
constexpr int N_ = 2048;
constexpr int M_ = 2048;
constexpr int S_ = 2049;                      // N+1 == M+1
constexpr long long PLANE = (long long)S_ * S_;

constexpr int Q_      = 8;     // contiguous columns per lane
constexpr int TILE_W  = 512;   // 64 lanes * 8 cols
constexpr int NTILE   = 4;     // col 2048 handled via "extra" lane-0 load
constexpr int RPW     = 16;    // rows per wave
constexpr int RPB     = 64;    // rows per block (4 waves)
constexpr int NSTRIPE = 32;    // 32*64 = 2048; row 2048 -> stripe 31 wave 3 (17 rows)

// D (doubles): [0]G1 [1]G2 [2]G1r [3]G2r [4]G1c [5]G2c [6]X0 [7]X1
//   [8..23] aL per batch  [24]P0 [25]P0q [26]P1 [27]P1q
constexpr int NDBL = 32;

typedef float f4u __attribute__((ext_vector_type(4), aligned(4)));   // 4B-aligned
typedef float f4a __attribute__((ext_vector_type(4)));               // 16B-aligned

// ---------------------------------------------------------------------------
// Kernel 1: gather pos0/pos1, zero D accumulators and colC.
// ---------------------------------------------------------------------------
__global__ void gather_pos(const float* __restrict__ scores,
                           const int* __restrict__ gt0,
                           const int* __restrict__ gt1,
                           float* __restrict__ pos0,
                           float* __restrict__ pos1,
                           float* __restrict__ colC,
                           double* __restrict__ D) {
  int idx = blockIdx.x * blockDim.x + threadIdx.x;
  if (idx < NDBL) D[idx] = 0.0;
  const int total = B_ * N_;
  if (idx < total) colC[idx] = 0.0f;          // B*M == B*N
  if (idx < total) {
    int b = idx >> 11;
    int i = idx & (N_ - 1);
    int g = gt0[idx];
    if (g == -1) g = M_;
    pos0[idx] = scores[(long long)b * PLANE + (long long)i * S_ + g];
  } else if (idx < 2 * total) {
    int k = idx - total;
    int b = k >> 11;
    int j = k & (M_ - 1);
    int g = gt1[k];
    if (g == -1) g = N_;
    pos1[k] = scores[(long long)b * PLANE + (long long)g * S_ + j];
  }
}

// ---------------------------------------------------------------------------
// Kernel 2: main sweep — R11 verbatim except balanced grid: (4,32,16) = 2048
// blocks = exactly 8/CU; stripe 31 wave 3 takes 17 rows (incl. row 2048).
// ---------------------------------------------------------------------------
__launch_bounds__(256)
__global__ void margin_main(const float* __restrict__ scores,
                            const float* __restrict__ pos0,
                            const float* __restrict__ pos1,
                            float* __restrict__ rowPart,   // [NTILE][B][N]
                            float* __restrict__ colC,      // [B][M] (atomic)
                            double* __restrict__ D) {
  const int tile = blockIdx.x;
  const int st   = blockIdx.y;
  const int b    = blockIdx.z;
  const int i0   = st * RPB;
  const int j0   = tile * TILE_W;
  const int tid  = threadIdx.x;
  const int lane = tid & 63;
  const int w    = tid >> 6;
  const int jbase = j0 + 8 * lane;

  __shared__ float lp0[RPB + 1];      // +1: row 2048 slot (stripe 31)
  __shared__ float ldsC[4][TILE_W];   // 8 KB
  __shared__ float ldsM[4][8];

  if (tid <= RPB) {
    int i = i0 + tid;
    lp0[tid] = (i < N_) ? pos0[b * N_ + i] : 0.0f;   // p0 = 0 for row 2048
  }

  float p1[Q_], cC[Q_];
  {
    const f4a plo = *(const f4a*)&pos1[b * M_ + jbase];
    const f4a phi = *(const f4a*)&pos1[b * M_ + jbase + 4];
    p1[0] = plo[0]; p1[1] = plo[1]; p1[2] = plo[2]; p1[3] = plo[3];
    p1[4] = phi[0]; p1[5] = phi[1]; p1[6] = phi[2]; p1[7] = phi[3];
  }
#pragma unroll
  for (int q = 0; q < Q_; ++q) cC[q] = 0.0f;
  float gs = 0.f, gq = 0.f, gsr = 0.f, gqr = 0.f,
        gsc = 0.f, gqc = 0.f, x0 = 0.f, x1 = 0.f;

  __syncthreads();

  const int ib = i0 + w * RPW;
  const int cap = (st == NSTRIPE - 1 && w == 3) ? RPW + 1 : RPW;  // 17 rows
  int rmax = S_ - ib;
  rmax = rmax < 0 ? 0 : (rmax > cap ? cap : rmax);
  const float* rowp = scores + (long long)b * PLANE + (long long)ib * S_ + jbase;
  const bool last_tile = (tile == NTILE - 1);

#pragma unroll 4
  for (int r = 0; r < rmax; ++r) {
    const int i = ib + r;
    const float p0 = lp0[w * RPW + r];
    const bool lastrow = (i == N_);

    const f4u v0 = *(const f4u*)(rowp);        // cols jbase..jbase+3
    const f4u v1 = *(const f4u*)(rowp + 4);    // cols jbase+4..jbase+7
    float s[Q_];
    s[0] = v0[0]; s[1] = v0[1]; s[2] = v0[2]; s[3] = v0[3];
    s[4] = v1[0]; s[5] = v1[1]; s[6] = v1[2]; s[7] = v1[3];
    float extra = 0.0f;
    if (last_tile && lane == 0) extra = rowp[TILE_W];   // column 2048

    float rC = 0.0f;
#pragma unroll
    for (int q = 0; q < Q_; ++q) {
      const float sv = s[q];
      const float sg = sv + GAMMA;
      rC += fmaxf(sg - p0, 0.0f);          // row clamp
      x0  = fmaf(p0, sv, x0);              // row cross (0 on lastrow)
      cC[q] += fmaxf(sg - p1[q], 0.0f);    // col clamp (row 2048 included)
      x1  = fmaf(p1[q], sv, x1);           // col cross
      gs += sv;
      gq  = fmaf(sv, sv, gq);
      if (lastrow) { gsr += sv; gqr = fmaf(sv, sv, gqr); }
    }
    if (last_tile && lane == 0) {          // col 2048: row pass + G1c/G2c
      rC  += fmaxf(extra + GAMMA - p0, 0.0f);
      x0   = fmaf(p0, extra, x0);
      gs  += extra; gq  = fmaf(extra, extra, gq);
      gsc += extra; gqc = fmaf(extra, extra, gqc);
      if (lastrow) { gsr += extra; gqr = fmaf(extra, extra, gqr); }
    }

#pragma unroll
    for (int off = 32; off; off >>= 1) rC += __shfl_xor(rC, off, 64);
    if (lane == 0 && !lastrow)
      rowPart[((long long)tile * B_ + b) * N_ + i] = rC;
    rowp += S_;
  }

  // ---- block-end reductions ----
  float m0 = gs, m1 = gq, m2 = gsr, m3 = gqr, m4 = gsc, m5 = gqc, m6 = x0, m7 = x1;
#pragma unroll
  for (int off = 32; off; off >>= 1) {
    m0 += __shfl_xor(m0, off, 64); m1 += __shfl_xor(m1, off, 64);
    m2 += __shfl_xor(m2, off, 64); m3 += __shfl_xor(m3, off, 64);
    m4 += __shfl_xor(m4, off, 64); m5 += __shfl_xor(m5, off, 64);
    m6 += __shfl_xor(m6, off, 64); m7 += __shfl_xor(m7, off, 64);
  }
  if (lane == 0) {
    ldsM[w][0] = m0; ldsM[w][1] = m1; ldsM[w][2] = m2; ldsM[w][3] = m3;
    ldsM[w][4] = m4; ldsM[w][5] = m5; ldsM[w][6] = m6; ldsM[w][7] = m7;
  }
  // contiguous per-lane columns: ldsC[w][8*lane + q]
#pragma unroll
  for (int q = 0; q < Q_; ++q) ldsC[w][8 * lane + q] = cC[q];

  __syncthreads();

  // cross-wave column reduce -> one atomicAdd per column (32 adds/address)
  {
    const float c0v = ldsC[0][tid] + ldsC[1][tid] + ldsC[2][tid] + ldsC[3][tid];
    const float c1v = ldsC[0][tid + 256] + ldsC[1][tid + 256] +
                      ldsC[2][tid + 256] + ldsC[3][tid + 256];
    atomicAdd(&colC[b * M_ + j0 + tid], c0v);
    atomicAdd(&colC[b * M_ + j0 + tid + 256], c1v);
  }
  if (tid < 8) {
    double v = (double)ldsM[0][tid] + (double)ldsM[1][tid] +
               (double)ldsM[2][tid] + (double)ldsM[3][tid];
    atomicAdd(&D[tid], v);
  }
}

// ---------------------------------------------------------------------------
// Kernel 3: logs + pos moments. Grid (8 slices, 16 b, 2 phases), 256 thr.
// ---------------------------------------------------------------------------
__global__ void finalize1(const float* __restrict__ rowPart,
                          const float* __restrict__ colC,
                          const float* __restrict__ pos0,
                          const float* __restrict__ pos1,
                          double* __restrict__ D) {
  const int slice = blockIdx.x;
  const int b     = blockIdx.y;
  const int phase = blockIdx.z;    // 0 = rows, 1 = cols
  const int tid   = threadIdx.x;
  const int lane  = tid & 63;
  const int w     = tid >> 6;
  const int idx   = slice * 256 + tid;   // always < 2048

  double aL, aP, aPq;
  if (phase == 0) {
    float r = 0.f;
#pragma unroll
    for (int t = 0; t < NTILE; ++t)
      r += rowPart[((long long)t * B_ + b) * N_ + idx];
    float p = pos0[b * N_ + idx];
    aL = log((double)r + 0.5);           // log(rowGap + 1), gt term folded
    aP = (double)p; aPq = (double)p * p;
  } else {
    float c = colC[b * M_ + idx];
    float p = pos1[b * M_ + idx];
    aL = log((double)c + 0.5);
    aP = (double)p; aPq = (double)p * p;
  }

#pragma unroll
  for (int off = 32; off; off >>= 1) {
    aL  += __shfl_xor(aL, off, 64);
    aP  += __shfl_xor(aP, off, 64);
    aPq += __shfl_xor(aPq, off, 64);
  }
  __shared__ double red[4][3];
  if (lane == 0) { red[w][0] = aL; red[w][1] = aP; red[w][2] = aPq; }
  __syncthreads();
  if (tid == 0) {
    atomicAdd(&D[8 + b], red[0][0] + red[1][0] + red[2][0] + red[3][0]);
    atomicAdd(&D[24 + 2 * phase], red[0][1] + red[1][1] + red[2][1] + red[3][1]);
    atomicAdd(&D[25 + 2 * phase], red[0][2] + red[1][2] + red[2][2] + red[3][2]);
  }
}

// ---------------------------------------------------------------------------
// Kernel 4: closed-form variance + output. One block, 64 threads.
// ---------------------------------------------------------------------------
__global__ void finalize2(const double* __restrict__ D,
                          float* __restrict__ out) {
  const int lane = threadIdx.x;
  const double G1 = D[0], G2 = D[1], G1r = D[2], G2r = D[3];
  const double G1c = D[4], G2c = D[5], X0 = D[6], X1 = D[7];
  const double P0 = D[24], P0q = D[25], P1 = D[26], P1q = D[27];
  const double SM = 2.0 * G1 - G1r - G1c - 2049.0 * (P0 + P1);
  const double SQ = 2.0 * G2 - G2r - G2c - 2.0 * (X0 + X1)
                    + 2049.0 * (P0q + P1q);
  const double cnt = 134217728.0;   // 2*B*N*M
  const double var = (SQ - SM * SM / cnt) / (cnt - 1.0);
  const double vl  = log(var + 1.0);
  if (lane < B_) out[lane] = (float)(D[8 + lane] / 4096.0 + vl);
}

// ---------------------------------------------------------------------------
extern "C" void kernel_launch(void* const* d_in, const int* in_sizes, int n_in,
                              void* d_out, int out_size, void* d_ws, size_t ws_size,
                              hipStream_t stream) {
  const float* scores = (const float*)d_in[0];
  const int*   gt0    = (const int*)d_in[1];
  const int*   gt1    = (const int*)d_in[2];
  float*       out    = (float*)d_out;

  double* D      = (double*)d_ws;                     // 32 doubles
  float* pos0    = (float*)((char*)d_ws + 256);
  float* pos1    = pos0 + (size_t)B_ * N_;
  float* rowPart = pos1 + (size_t)B_ * M_;            // NTILE*B*N
  float* colC    = rowPart + (size_t)NTILE * B_ * N_; // B*M

  const int gth = 2 * B_ * N_;
  gather_pos<<<(gth + 255) / 256, 256, 0, stream>>>(scores, gt0, gt1,
                                                    pos0, pos1, colC, D);

  dim3 grid(NTILE, NSTRIPE, B_);    // (4, 32, 16) = 2048 blocks
  margin_main<<<grid, 256, 0, stream>>>(scores, pos0, pos1,
                                        rowPart, colC, D);

  dim3 fgrid(8, B_, 2);
  finalize1<<<fgrid, 256, 0, stream>>>(rowPart, colC, pos0, pos1, D);
  finalize2<<<1, 64, 0, stream>>>(D, out);
}